// Round 1
// baseline (174.911 us; speedup 1.0000x reference)
//
#include <hip/hip_runtime.h>
#include <hip/hip_bf16.h>

// 1-NN VQ via split-bf16 MFMA + exact fp32 refinement.
//   score[q][k] = csq[k] - 2*dot(q,c_k); out = argmin_k (lowest-k tie-break).
// Phase 0 (knn_prep): codebook -> bf16 hi/lo fragment-ready cbB (part-major) + csq.
// Phase A (knn_mfma): 128 q/block, 4 waves; wave = 2 m-tiles x ALL 16 n-tiles
//   (acc[2][16] = 128 AGPR). A (query) split-converted ONCE into registers
//   (ah/al[2][4] = 64 VGPR) in the prologue.
// r10 vs r9: LDS staging of B REMOVED entirely (codebook = 128 KiB, L2-resident
//   for all 1024 blocks -- staging + 3 barriers + vmcnt(0) drains were pure
//   phase-serialization overhead; guide Common-mistake #7). hi/lo phases fused:
//   per (kb,t) load bh/bl direct from global (coalesced 1 KiB/wave-instr,
//   compile-time offsets off one per-lane base) + 6 MFMAs. Manual 1-deep
//   register double-buffer bh[2]/bl[2] (static idx). Kernel now has ZERO LDS
//   and ZERO __syncthreads -- waves fully independent, A-load (HBM) / B-load
//   (L2) / MFMA / epilogue VALU overlap across 8 waves/CU.
//   dot ~= qh.ch + ql.ch + qh.cl (3-product, score err ~1.9e-3); per-wave
//   top-2 over all 256 codes; gap < T=0.004 -> worklist.
// Phase B (knn_refine): exact fp32 rescan, block-per-query.
// Budget: 128 acc + 64 A + 16 B-buf + ~25 addr ~= 235 regs (cap 256 @ 2 w/EU).

typedef __bf16 bf16x8 __attribute__((ext_vector_type(8)));
typedef float  floatx4 __attribute__((ext_vector_type(4)));

#define MFMA16 __builtin_amdgcn_mfma_f32_16x16x32_bf16

#define CNT_OFF 0
#define CSQ_OFF 1024
#define CBB_OFF 4096
#define WL_OFF  (4096 + 131072)
#define WL_CAP  32768
#define T_FLAG  0.004f

__device__ __forceinline__ unsigned fmap(float f) {
    unsigned u = __float_as_uint(f);
    return (u & 0x80000000u) ? ~u : (u | 0x80000000u);
}
__device__ __forceinline__ float unfmap(unsigned u) {
    unsigned b = (u & 0x80000000u) ? (u ^ 0x80000000u) : ~u;
    return __uint_as_float(b);
}

// ---------------- Phase 0: codebook split, part-major fragment layout, csq ----------------
// cbB element index = part*32768 + ((t4*4 + kb)*64 + ln)*8 + j
//   part: 0=hi 1=lo; t4 = ntile 0..15; kb = k-chunk 0..3;
//   lane ln: n = t4*16 + (ln&15), k = kb*32 + (ln>>4)*8 + j.
__global__ void knn_prep(const float* __restrict__ cb, __bf16* __restrict__ cbB,
                         float* __restrict__ csq, int* __restrict__ cnt) {
    const int tid = threadIdx.x;
    const int id = blockIdx.x * 256 + tid;       // 0..8191
    if (id == 0) *cnt = 0;
    const int part = id >> 12;
    const int rem = id & 4095;
    const int t4 = rem >> 8;
    const int kb = (rem >> 6) & 3;
    const int ln = id & 63;
    const int n = t4 * 16 + (ln & 15);
    const int k0 = kb * 32 + (ln >> 4) * 8;
    const float* src = cb + (size_t)n * 128 + k0;
    union { __bf16 h[8]; uint4 u; } p;
#pragma unroll
    for (int j = 0; j < 8; ++j) {
        float f = src[j];
        __bf16 hh = (__bf16)f;
        p.h[j] = (part == 0) ? hh : (__bf16)(f - (float)hh);
    }
    *(uint4*)(cbB + (size_t)id * 8) = p.u;

    if (blockIdx.x == 0) {
        const float4* row = (const float4*)(cb + (size_t)tid * 128);
        float a0 = 0.f, a1 = 0.f, a2 = 0.f, a3 = 0.f;
#pragma unroll 8
        for (int j = 0; j < 32; ++j) {
            float4 v = row[j];
            a0 = fmaf(v.x, v.x, a0);
            a1 = fmaf(v.y, v.y, a1);
            a2 = fmaf(v.z, v.z, a2);
            a3 = fmaf(v.w, v.w, a3);
        }
        csq[tid] = (a0 + a1) + (a2 + a3);
    }
}

// ---------------- Phase A: MFMA scores + top-2 + flag (no LDS, no barriers) ----------------
__global__ __launch_bounds__(256, 2) void knn_mfma(const float* __restrict__ x,
                                                   const __bf16* __restrict__ cbB,
                                                   const float* __restrict__ csq_g,
                                                   int* __restrict__ out,
                                                   int* __restrict__ cnt,
                                                   int* __restrict__ wl) {
    const int tid = threadIdx.x;
    const int wave = tid >> 6;
    const int lane = tid & 63;
    const int rl = lane & 15;                    // m/n col within tile
    const int kg = lane >> 4;                    // k-group 0..3

    // ---- A: load + split-convert this wave's 2 m-tiles into registers ----
    const float* xq = x + ((size_t)blockIdx.x * 128 + wave * 32) * 128;
    bf16x8 ah[2][4], al[2][4];
#pragma unroll
    for (int m = 0; m < 2; ++m) {
#pragma unroll
        for (int kb = 0; kb < 4; ++kb) {
            const float* s = xq + (size_t)(m * 16 + rl) * 128 + kb * 32 + kg * 8;
            float4 f0 = *(const float4*)(s);
            float4 f1 = *(const float4*)(s + 4);
            float f[8] = {f0.x, f0.y, f0.z, f0.w, f1.x, f1.y, f1.z, f1.w};
            union { __bf16 h[8]; bf16x8 v; } ph, pl;
#pragma unroll
            for (int j = 0; j < 8; ++j) {
                __bf16 hh = (__bf16)f[j];
                ph.h[j] = hh;
                pl.h[j] = (__bf16)(f[j] - (float)hh);
            }
            ah[m][kb] = ph.v;
            al[m][kb] = pl.v;
        }
    }

    floatx4 acc[2][16];
#pragma unroll
    for (int m = 0; m < 2; ++m)
#pragma unroll
        for (int t = 0; t < 16; ++t) acc[m][t] = (floatx4){0.f, 0.f, 0.f, 0.f};

    // ---- fused K-loop: B direct from global (L2-resident), 1-deep reg dbuf ----
    // element offset = part*32768 + (t*4+kb)*512 + lane*8
    const __bf16* bp = cbB + lane * 8;
#define BOFF(part, kb, t) ((part) * 32768 + ((t) * 4 + (kb)) * 512)
    bf16x8 bh[2], bl[2];
    bh[0] = *(const bf16x8*)(bp + BOFF(0, 0, 0));
    bl[0] = *(const bf16x8*)(bp + BOFF(1, 0, 0));
#pragma unroll
    for (int i = 0; i < 64; ++i) {
        const int kb = i >> 4;                   // static (fully unrolled)
        const int t = i & 15;
        const int cur = i & 1;
        if (i < 63) {
            const int ni = i + 1;
            const int nkb = ni >> 4;
            const int nt = ni & 15;
            bh[cur ^ 1] = *(const bf16x8*)(bp + BOFF(0, nkb, nt));
            bl[cur ^ 1] = *(const bf16x8*)(bp + BOFF(1, nkb, nt));
        }
        acc[0][t] = MFMA16(ah[0][kb], bh[cur], acc[0][t], 0, 0, 0);
        acc[1][t] = MFMA16(ah[1][kb], bh[cur], acc[1][t], 0, 0, 0);
        acc[0][t] = MFMA16(al[0][kb], bh[cur], acc[0][t], 0, 0, 0);
        acc[1][t] = MFMA16(al[1][kb], bh[cur], acc[1][t], 0, 0, 0);
        acc[0][t] = MFMA16(ah[0][kb], bl[cur], acc[0][t], 0, 0, 0);
        acc[1][t] = MFMA16(ah[1][kb], bl[cur], acc[1][t], 0, 0, 0);
    }
#undef BOFF

    // ---- epilogue: per-wave top-2 over ALL 256 codes (FULLY unrolled) ----
    float cs[16];
#pragma unroll
    for (int t = 0; t < 16; ++t) cs[t] = csq_g[t * 16 + rl];   // 1 KiB, L1-hot

#pragma unroll
    for (int m = 0; m < 2; ++m) {
#pragma unroll
        for (int r = 0; r < 4; ++r) {
            unsigned long long b = ~0ULL, s = ~0ULL;
#pragma unroll
            for (int t = 0; t < 16; ++t) {
                const int n = t * 16 + rl;
                float score = fmaf(-2.0f, acc[m][t][r], cs[t]);
                unsigned long long key =
                    ((unsigned long long)fmap(score) << 32) | (unsigned)n;
                if (key < b) { s = b; b = key; }
                else if (key < s) { s = key; }
            }
#pragma unroll
            for (int d = 1; d < 16; d <<= 1) {
                unsigned long long ob = __shfl_xor(b, d);
                unsigned long long os = __shfl_xor(s, d);
                unsigned long long nb = ob < b ? ob : b;
                unsigned long long mx = ob < b ? b : ob;
                unsigned long long mn = os < s ? os : s;
                b = nb;
                s = mx < mn ? mx : mn;
            }
            if (rl == 0) {
                const size_t qg = (size_t)blockIdx.x * 128 + wave * 32
                                  + m * 16 + kg * 4 + r;
                out[qg] = (int)(unsigned)(b & 0xFFFFFFFFull);
                float f1 = unfmap((unsigned)(b >> 32));
                float f2 = unfmap((unsigned)(s >> 32));
                if (f2 - f1 < T_FLAG) {
                    int idx = atomicAdd(cnt, 1);
                    if (idx < WL_CAP) wl[idx] = (int)qg;
                }
            }
        }
    }
}

// ---------------- Phase B: exact fp32 rescan, block-per-query ----------------
__global__ __launch_bounds__(256) void knn_refine(const float* __restrict__ x,
                                                  const float* __restrict__ cb,
                                                  const float* __restrict__ csq_g,
                                                  const int* __restrict__ wl,
                                                  const int* __restrict__ cnt,
                                                  int* __restrict__ out) {
    __shared__ unsigned long long sP[4];
    const int tid = threadIdx.x;           // == code index k
    const int lane = tid & 63;
    const int wave = tid >> 6;

    int n = *cnt;
    if (n > WL_CAP) n = WL_CAP;
    const float mycsq = csq_g[tid];
    const float4* cr = (const float4*)(cb + (size_t)tid * 128);

    for (int i = blockIdx.x; i < n; i += gridDim.x) {
        const int q = wl[i];
        const float4* qr = (const float4*)(x + (size_t)q * 128);
        float a0 = 0.f, a1 = 0.f, a2 = 0.f, a3 = 0.f;
#pragma unroll 8
        for (int c4 = 0; c4 < 32; ++c4) {
            float4 qv = qr[c4];            // broadcast (same addr all lanes)
            float4 cv = cr[c4];
            a0 = fmaf(qv.x, cv.x, a0);
            a1 = fmaf(qv.y, cv.y, a1);
            a2 = fmaf(qv.z, cv.z, a2);
            a3 = fmaf(qv.w, cv.w, a3);
        }
        float dot = (a0 + a1) + (a2 + a3);
        float score = fmaf(-2.0f, dot, mycsq);
        unsigned long long key =
            ((unsigned long long)fmap(score) << 32) | (unsigned)tid;
#pragma unroll
        for (int d = 1; d < 64; d <<= 1) {
            unsigned long long o = __shfl_xor(key, d);
            key = o < key ? o : key;
        }
        if (lane == 0) sP[wave] = key;
        __syncthreads();
        if (tid == 0) {
            unsigned long long b = sP[0];
            unsigned long long o;
            o = sP[1]; b = o < b ? o : b;
            o = sP[2]; b = o < b ? o : b;
            o = sP[3]; b = o < b ? o : b;
            out[q] = (int)(unsigned)(b & 0xFFFFFFFFull);
        }
        __syncthreads();
    }
}

extern "C" void kernel_launch(void* const* d_in, const int* in_sizes, int n_in,
                              void* d_out, int out_size, void* d_ws, size_t ws_size,
                              hipStream_t stream) {
    const float* x = (const float*)d_in[0];
    const float* cb = (const float*)d_in[1];
    int* out = (int*)d_out;

    char* ws = (char*)d_ws;
    int* cnt = (int*)(ws + CNT_OFF);
    float* csq = (float*)(ws + CSQ_OFF);
    __bf16* cbB = (__bf16*)(ws + CBB_OFF);
    int* wl = (int*)(ws + WL_OFF);

    const int M = in_sizes[0] / 128;     // 131072

    knn_prep<<<32, 256, 0, stream>>>(cb, cbB, csq, cnt);
    knn_mfma<<<M / 128, 256, 0, stream>>>(x, cbB, csq, out, cnt, wl);
    knn_refine<<<240, 256, 0, stream>>>(x, cb, csq, wl, cnt, out);
}

// Round 4
// 132.858 us; speedup vs baseline: 1.3165x; 1.3165x over previous
//
#include <hip/hip_runtime.h>
#include <hip/hip_bf16.h>

// 1-NN VQ via split-bf16 MFMA + exact fp32 refinement.
//   score[q][k] = csq[k] - 2*dot(q,c_k); out = argmin_k (lowest-k tie-break).
// Phase 0 (knn_prep): codebook -> bf16 hi/lo fragment-ready cbB (kb-major) + csq.
// Phase A (knn_mfma): 128 q/block, 4 waves; wave = 2 m-tiles x ALL 16 n-tiles
//   (acc[2][16] = 128 AGPR). A (query) split-converted ONCE into registers.
// r11 vs r10: r10 spilled ~65 dwords/thread (WRITE_SIZE 68 MB of scratch;
//   VGPR_Count=128 cap with 128 AGPR acc): fully-unrolled direct-global B
//   needed 128 materialized addresses + hoisted loads > 128 arch regs.
//   Fix: B staged per-kb (32 KB hi+lo fused chunk) into 64 KB double-buffered
//   LDS via global_load_lds width=16 (ZERO data regs, ZERO addr explosion).
//   Minimum 2-phase template (guide 5.5 T3): stage kb+1 | compute kb (16 t x
//   {2 ds_read_b128 + 6 MFMA}) | one __syncthreads per kb (implicit vmcnt(0)
//   drain = arrival sync, covered by 96 MFMAs). cbB reordered kb-major so the
//   staged chunk is linear (gload_lds needs linear dest, guide m104).
//   dot ~= qh.ch + ql.ch + qh.cl (3-product, score err ~1.9e-3); per-wave
//   top-2 over all 256 codes; gap < T=0.004 -> worklist.
// Phase B (knn_refine): exact fp32 rescan, block-per-query.
// Arch budget: 64 A + ~32 B-frag in flight + ~15 addr ~= 115 <= 128 (no spill).
// r13: never benched (broker timeouts r1-r3). FIXED r12 resubmit typo: 6th
//   MFMA operand was al[1][kb] (ql.cl) instead of ah[1][kb] (qh.cl) -- would
//   have dropped the m=1 correction term (err ~1e-2 >> T_FLAG) -> wrong argmin.

typedef __bf16 bf16x8 __attribute__((ext_vector_type(8)));
typedef float  floatx4 __attribute__((ext_vector_type(4)));

#define MFMA16 __builtin_amdgcn_mfma_f32_16x16x32_bf16

#define CNT_OFF 0
#define CSQ_OFF 1024
#define CBB_OFF 4096
#define WL_OFF  (4096 + 131072)
#define WL_CAP  32768
#define T_FLAG  0.004f

typedef __attribute__((address_space(1))) const unsigned int gu32;
typedef __attribute__((address_space(3))) unsigned int lu32;

__device__ __forceinline__ unsigned fmap(float f) {
    unsigned u = __float_as_uint(f);
    return (u & 0x80000000u) ? ~u : (u | 0x80000000u);
}
__device__ __forceinline__ float unfmap(unsigned u) {
    unsigned b = (u & 0x80000000u) ? (u ^ 0x80000000u) : ~u;
    return __uint_as_float(b);
}

// ---------------- Phase 0: codebook split, kb-major fragment layout, csq ----------------
// cbB element index = ((kb*16 + t)*2 + part)*512 + ln*8 + j   (= id*8 below)
//   kb = k-chunk 0..3; t = ntile 0..15; part: 0=hi 1=lo;
//   lane ln: n = t*16 + (ln&15), k = kb*32 + (ln>>4)*8 + j.
// kb-major => per-kb chunk is 32 KB CONTIGUOUS (hi/lo fused) for linear LDS staging.
__global__ void knn_prep(const float* __restrict__ cb, __bf16* __restrict__ cbB,
                         float* __restrict__ csq, int* __restrict__ cnt) {
    const int tid = threadIdx.x;
    const int id = blockIdx.x * 256 + tid;       // 0..8191
    if (id == 0) *cnt = 0;
    const int ln = id & 63;
    const int part = (id >> 6) & 1;
    const int step = id >> 7;                    // kb*16 + t
    const int t4 = step & 15;
    const int kb = step >> 4;
    const int n = t4 * 16 + (ln & 15);
    const int k0 = kb * 32 + (ln >> 4) * 8;
    const float* src = cb + (size_t)n * 128 + k0;
    union { __bf16 h[8]; uint4 u; } p;
#pragma unroll
    for (int j = 0; j < 8; ++j) {
        float f = src[j];
        __bf16 hh = (__bf16)f;
        p.h[j] = (part == 0) ? hh : (__bf16)(f - (float)hh);
    }
    *(uint4*)(cbB + (size_t)id * 8) = p.u;

    if (blockIdx.x == 0) {
        const float4* row = (const float4*)(cb + (size_t)tid * 128);
        float a0 = 0.f, a1 = 0.f, a2 = 0.f, a3 = 0.f;
#pragma unroll 8
        for (int j = 0; j < 32; ++j) {
            float4 v = row[j];
            a0 = fmaf(v.x, v.x, a0);
            a1 = fmaf(v.y, v.y, a1);
            a2 = fmaf(v.z, v.z, a2);
            a3 = fmaf(v.w, v.w, a3);
        }
        csq[tid] = (a0 + a1) + (a2 + a3);
    }
}

// ---------------- Phase A: MFMA scores + top-2 + flag ----------------
__global__ __launch_bounds__(256, 2) void knn_mfma(const float* __restrict__ x,
                                                   const __bf16* __restrict__ cbB,
                                                   const float* __restrict__ csq_g,
                                                   int* __restrict__ out,
                                                   int* __restrict__ cnt,
                                                   int* __restrict__ wl) {
    __shared__ __bf16 sB[32768];                 // 64 KB: 2 x 32 KB kb-chunks

    const int tid = threadIdx.x;
    const int wave = tid >> 6;
    const int lane = tid & 63;
    const int rl = lane & 15;                    // m/n col within tile
    const int kg = lane >> 4;                    // k-group 0..3

    // per-lane global src / wave-uniform LDS dst for staging (8 x 1 KB per kb)
    const char* gsrc = (const char*)cbB + wave * 8192 + lane * 16;
    char* ldst = (char*)sB + wave * 8192;

    // ---- issue stage of kb=0 into buf0 FIRST (L2 latency hides under A-conv) ----
#pragma unroll
    for (int i = 0; i < 8; ++i)
        __builtin_amdgcn_global_load_lds((gu32*)(gsrc + i * 1024),
                                         (lu32*)(ldst + i * 1024), 16, 0, 0);

    // ---- A: load + split-convert this wave's 2 m-tiles into registers ----
    const float* xq = x + ((size_t)blockIdx.x * 128 + wave * 32) * 128;
    bf16x8 ah[2][4], al[2][4];
#pragma unroll
    for (int m = 0; m < 2; ++m) {
#pragma unroll
        for (int kb = 0; kb < 4; ++kb) {
            const float* s = xq + (size_t)(m * 16 + rl) * 128 + kb * 32 + kg * 8;
            float4 f0 = *(const float4*)(s);
            float4 f1 = *(const float4*)(s + 4);
            float f[8] = {f0.x, f0.y, f0.z, f0.w, f1.x, f1.y, f1.z, f1.w};
            union { __bf16 h[8]; bf16x8 v; } ph, pl;
#pragma unroll
            for (int j = 0; j < 8; ++j) {
                __bf16 hh = (__bf16)f[j];
                ph.h[j] = hh;
                pl.h[j] = (__bf16)(f[j] - (float)hh);
            }
            ah[m][kb] = ph.v;
            al[m][kb] = pl.v;
        }
    }

    floatx4 acc[2][16];
#pragma unroll
    for (int m = 0; m < 2; ++m)
#pragma unroll
        for (int t = 0; t < 16; ++t) acc[m][t] = (floatx4){0.f, 0.f, 0.f, 0.f};

    __syncthreads();                             // kb=0 chunk landed (vmcnt drain)

    // ---- 2-phase K-loop: stage kb+1 | compute kb | barrier ----
#pragma unroll
    for (int kb = 0; kb < 4; ++kb) {
        const int buf = kb & 1;
        if (kb < 3) {
            const char* g = gsrc + (kb + 1) * 32768;
            char* l = ldst + (buf ^ 1) * 32768;
#pragma unroll
            for (int i = 0; i < 8; ++i)
                __builtin_amdgcn_global_load_lds((gu32*)(g + i * 1024),
                                                 (lu32*)(l + i * 1024), 16, 0, 0);
        }
        // fragment (t,part) at byte offset buf*32768 + (t*2+part)*1024 + lane*16
        const __bf16* sbase = sB + (buf << 14) + lane * 8;
#pragma unroll
        for (int t = 0; t < 16; ++t) {
            bf16x8 bh = *(const bf16x8*)(sbase + t * 1024);
            bf16x8 bl = *(const bf16x8*)(sbase + t * 1024 + 512);
            acc[0][t] = MFMA16(ah[0][kb], bh, acc[0][t], 0, 0, 0);
            acc[1][t] = MFMA16(ah[1][kb], bh, acc[1][t], 0, 0, 0);
            acc[0][t] = MFMA16(al[0][kb], bh, acc[0][t], 0, 0, 0);
            acc[1][t] = MFMA16(al[1][kb], bh, acc[1][t], 0, 0, 0);
            acc[0][t] = MFMA16(ah[0][kb], bl, acc[0][t], 0, 0, 0);
            acc[1][t] = MFMA16(ah[1][kb], bl, acc[1][t], 0, 0, 0);
        }
        if (kb < 3) __syncthreads();             // readers done + next chunk landed
    }

    // ---- epilogue: per-wave top-2 over ALL 256 codes (FULLY unrolled) ----
    float cs[16];
#pragma unroll
    for (int t = 0; t < 16; ++t) cs[t] = csq_g[t * 16 + rl];   // 1 KiB, L1-hot

#pragma unroll
    for (int m = 0; m < 2; ++m) {
#pragma unroll
        for (int r = 0; r < 4; ++r) {
            unsigned long long b = ~0ULL, s = ~0ULL;
#pragma unroll
            for (int t = 0; t < 16; ++t) {
                const int n = t * 16 + rl;
                float score = fmaf(-2.0f, acc[m][t][r], cs[t]);
                unsigned long long key =
                    ((unsigned long long)fmap(score) << 32) | (unsigned)n;
                if (key < b) { s = b; b = key; }
                else if (key < s) { s = key; }
            }
#pragma unroll
            for (int d = 1; d < 16; d <<= 1) {
                unsigned long long ob = __shfl_xor(b, d);
                unsigned long long os = __shfl_xor(s, d);
                unsigned long long nb = ob < b ? ob : b;
                unsigned long long mx = ob < b ? b : ob;
                unsigned long long mn = os < s ? os : s;
                b = nb;
                s = mx < mn ? mx : mn;
            }
            if (rl == 0) {
                const size_t qg = (size_t)blockIdx.x * 128 + wave * 32
                                  + m * 16 + kg * 4 + r;
                out[qg] = (int)(unsigned)(b & 0xFFFFFFFFull);
                float f1 = unfmap((unsigned)(b >> 32));
                float f2 = unfmap((unsigned)(s >> 32));
                if (f2 - f1 < T_FLAG) {
                    int idx = atomicAdd(cnt, 1);
                    if (idx < WL_CAP) wl[idx] = (int)qg;
                }
            }
        }
    }
}

// ---------------- Phase B: exact fp32 rescan, block-per-query ----------------
__global__ __launch_bounds__(256) void knn_refine(const float* __restrict__ x,
                                                  const float* __restrict__ cb,
                                                  const float* __restrict__ csq_g,
                                                  const int* __restrict__ wl,
                                                  const int* __restrict__ cnt,
                                                  int* __restrict__ out) {
    __shared__ unsigned long long sP[4];
    const int tid = threadIdx.x;           // == code index k
    const int lane = tid & 63;
    const int wave = tid >> 6;

    int n = *cnt;
    if (n > WL_CAP) n = WL_CAP;
    const float mycsq = csq_g[tid];
    const float4* cr = (const float4*)(cb + (size_t)tid * 128);

    for (int i = blockIdx.x; i < n; i += gridDim.x) {
        const int q = wl[i];
        const float4* qr = (const float4*)(x + (size_t)q * 128);
        float a0 = 0.f, a1 = 0.f, a2 = 0.f, a3 = 0.f;
#pragma unroll 8
        for (int c4 = 0; c4 < 32; ++c4) {
            float4 qv = qr[c4];            // broadcast (same addr all lanes)
            float4 cv = cr[c4];
            a0 = fmaf(qv.x, cv.x, a0);
            a1 = fmaf(qv.y, cv.y, a1);
            a2 = fmaf(qv.z, cv.z, a2);
            a3 = fmaf(qv.w, cv.w, a3);
        }
        float dot = (a0 + a1) + (a2 + a3);
        float score = fmaf(-2.0f, dot, mycsq);
        unsigned long long key =
            ((unsigned long long)fmap(score) << 32) | (unsigned)tid;
#pragma unroll
        for (int d = 1; d < 64; d <<= 1) {
            unsigned long long o = __shfl_xor(key, d);
            key = o < key ? o : key;
        }
        if (lane == 0) sP[wave] = key;
        __syncthreads();
        if (tid == 0) {
            unsigned long long b = sP[0];
            unsigned long long o;
            o = sP[1]; b = o < b ? o : b;
            o = sP[2]; b = o < b ? o : b;
            o = sP[3]; b = o < b ? o : b;
            out[q] = (int)(unsigned)(b & 0xFFFFFFFFull);
        }
        __syncthreads();
    }
}

extern "C" void kernel_launch(void* const* d_in, const int* in_sizes, int n_in,
                              void* d_out, int out_size, void* d_ws, size_t ws_size,
                              hipStream_t stream) {
    const float* x = (const float*)d_in[0];
    const float* cb = (const float*)d_in[1];
    int* out = (int*)d_out;

    char* ws = (char*)d_ws;
    int* cnt = (int*)(ws + CNT_OFF);
    float* csq = (float*)(ws + CSQ_OFF);
    __bf16* cbB = (__bf16*)(ws + CBB_OFF);
    int* wl = (int*)(ws + WL_OFF);

    const int M = in_sizes[0] / 128;     // 131072

    knn_prep<<<32, 256, 0, stream>>>(cb, cbB, csq, cnt);
    knn_mfma<<<M / 128, 256, 0, stream>>>(x, cbB, csq, out, cnt, wl);
    knn_refine<<<240, 256, 0, stream>>>(x, cb, csq, wl, cnt, out);
}